// Round 6
// baseline (1292.080 us; speedup 1.0000x reference)
//
#include <hip/hip_runtime.h>
#include <hip/hip_bf16.h>

// HunyuanTopKGate: x[4096,4096] fp32, wg[64,4096] fp32 ->
//   combine_weights [T,E,C] fp32 ++ dispatch_mask [T,E,C] (as fp32 0/1)
// C = 2268 -> 4.76 GB output zero-fill (~760us at 6.2 TB/s) is pole #1.
//
// Round 16: R15 killed the dispatch-overhead theory (6->3 dispatches: no
// change). The model that fits ALL rounds: total = fill(760) + gemm
// phase(~480, CONSTANT across fp64/MFMA/occupancy changes) + tails. A
// 480us compute-invariant = ingest bound: 64MB of x / 480us = 133 GB/s
// = host-link speed -> d_in is slow memory, every gemm was PCIe-bound
// on x. (R12's 1.16GB ws poison at 39 GB/s already proved harness
// buffers can be non-HBM.) Fix: one dispatch runs {fill blocks || copy
// blocks streaming x -> ws}; PCIe-read overlaps HBM-write fill. Then
// R10-verbatim gemm reads the HBM copy (bit-identical fp32 -> absmax
// unchanged 0.0004882812), then topk, scatter. If ws too small: fall
// back to direct x (work-identical to R15 -> neutral). If theory wrong:
// copy hides under fill -> neutral. If right: total ~900-950.
//
// ws: partial[8][4096][64] f64 (16MB) | idx_kt | w_kt | xcopy[4096][4096] f32 (64MB)

#define TOK 4096
#define HID 4096
#define NE  64
#define NK  8
#define NSPLIT 8

typedef __attribute__((ext_vector_type(8))) short short8;   // 8 bf16
typedef __attribute__((ext_vector_type(4))) float f32x4;

__device__ __forceinline__ short f2bf(float f) {
  __hip_bfloat16 h = __float2bfloat16(f);   // RNE
  return *reinterpret_cast<short*>(&h);
}
__device__ __forceinline__ float bf2f(short s) {
  unsigned u = ((unsigned)(unsigned short)s) << 16;
  return __uint_as_float(u);
}
__device__ __forceinline__ void cvt3(float f, short& s0, short& s1, short& s2) {
  s0 = f2bf(f);
  float r1 = f - bf2f(s0);
  s1 = f2bf(r1);
  float r2 = r1 - bf2f(s1);
  s2 = f2bf(r2);
}

// ---------------- 1. fill_copy: copy blocks (bx<ncopy) + fill blocks ------
// copy: 256 blocks stream x (4.19M float4s, 65536 threads, 64 f4 each,
// coalesced grid-stride) into xcopy. Scheduled FIRST so the PCIe read
// starts at t=0 and hides under the 4.76GB fill.
// fill: R15-proven plain dwordx4 grid-stride stores, 4x unrolled.
__global__ __launch_bounds__(256) void fill_copy(
    const float* __restrict__ x, float* __restrict__ xcopy, int ncopy,
    int nfill, float* __restrict__ out, int out_n) {
  const int bx  = blockIdx.x;
  const int tid = threadIdx.x;

  if (bx < ncopy) {                     // ---- copy branch ----
    const size_t nf4    = (size_t)TOK * HID / 4;        // 4,194,304
    const size_t stride = (size_t)ncopy * 256;
    const f32x4* x4 = (const f32x4*)x;
    f32x4* c4 = (f32x4*)xcopy;
    for (size_t i = (size_t)bx * 256 + tid; i < nf4; i += stride)
      c4[i] = x4[i];
    return;
  }

  // ---- fill branch ----
  const int    fid    = bx - ncopy;
  const size_t n4     = ((size_t)(unsigned)out_n) >> 2;
  const size_t stride = (size_t)nfill * 256;
  f32x4* o4 = (f32x4*)out;
  const f32x4 z4 = (f32x4){0.f, 0.f, 0.f, 0.f};
  size_t i = (size_t)fid * 256 + tid;
  for (; i + 3 * stride < n4; i += 4 * stride) {
    o4[i]              = z4;
    o4[i + stride]     = z4;
    o4[i + 2 * stride] = z4;
    o4[i + 3 * stride] = z4;
  }
  for (; i < n4; i += stride) o4[i] = z4;
  if (fid == 0 && tid == 0)             // out_n % 4 == 0 -> empty, kept safe
    for (size_t i2 = n4 << 2; i2 < (size_t)(unsigned)out_n; ++i2) out[i2] = 0.f;
}

// ---------------- 2. bf16x3 MFMA GEMM (R10 verbatim, reads xsrc) ----------
// Grid (64 token-tiles, 8 k-slabs), 256 thr = 4 waves. LDS: 3 bf16
// planes for x and wg, stride 72 shorts (16B-aligned b128 frags).
__global__ __launch_bounds__(256) void gemm_bf16x3(
    const float* __restrict__ x, const float* __restrict__ wg,
    double* __restrict__ partial, int kchunk) {
  __shared__ __align__(16) short XA[3][64][72];   // 27.6 KB
  __shared__ __align__(16) short WB[3][64][72];   // 27.6 KB
  const int tid = threadIdx.x;
  const int t0   = blockIdx.x * 64;
  const int k0   = blockIdx.y * kchunk;
  const int lane = tid & 63;
  const int w    = tid >> 6;
  const int m    = lane & 15;       // frag row/col within 16
  const int q    = lane >> 4;       // quad
  const int lrow = tid >> 2;        // staging: 4 threads per row
  const int lq   = tid & 3;         // 16 floats each

  f32x4 acc[4];
#pragma unroll
  for (int nt = 0; nt < 4; ++nt) acc[nt] = (f32x4){0.f, 0.f, 0.f, 0.f};

  for (int s = 0; s < kchunk; s += 64) {
    const int kk = k0 + s;
#pragma unroll
    for (int c = 0; c < 4; ++c) {
      const int col = lq * 16 + c * 4;
      float4 xv = *(const float4*)&x [(size_t)(t0 + lrow) * HID + kk + col];
      float4 wv = *(const float4*)&wg[(size_t)lrow * HID + kk + col];
      short4 p0, p1, p2;
      cvt3(xv.x, p0.x, p1.x, p2.x);  cvt3(xv.y, p0.y, p1.y, p2.y);
      cvt3(xv.z, p0.z, p1.z, p2.z);  cvt3(xv.w, p0.w, p1.w, p2.w);
      *(short4*)&XA[0][lrow][col] = p0;
      *(short4*)&XA[1][lrow][col] = p1;
      *(short4*)&XA[2][lrow][col] = p2;
      cvt3(wv.x, p0.x, p1.x, p2.x);  cvt3(wv.y, p0.y, p1.y, p2.y);
      cvt3(wv.z, p0.z, p1.z, p2.z);  cvt3(wv.w, p0.w, p1.w, p2.w);
      *(short4*)&WB[0][lrow][col] = p0;
      *(short4*)&WB[1][lrow][col] = p1;
      *(short4*)&WB[2][lrow][col] = p2;
    }
    __syncthreads();
#pragma unroll
    for (int kc = 0; kc < 64; kc += 32) {
      short8 a0 = *(const short8*)&XA[0][w * 16 + m][kc + q * 8];
      short8 a1 = *(const short8*)&XA[1][w * 16 + m][kc + q * 8];
      short8 a2 = *(const short8*)&XA[2][w * 16 + m][kc + q * 8];
#pragma unroll
      for (int nt = 0; nt < 4; ++nt) {
        short8 b0 = *(const short8*)&WB[0][nt * 16 + m][kc + q * 8];
        short8 b1 = *(const short8*)&WB[1][nt * 16 + m][kc + q * 8];
        short8 b2 = *(const short8*)&WB[2][nt * 16 + m][kc + q * 8];
        acc[nt] = __builtin_amdgcn_mfma_f32_16x16x32_bf16(a0, b0, acc[nt], 0, 0, 0);
        acc[nt] = __builtin_amdgcn_mfma_f32_16x16x32_bf16(a0, b1, acc[nt], 0, 0, 0);
        acc[nt] = __builtin_amdgcn_mfma_f32_16x16x32_bf16(a1, b0, acc[nt], 0, 0, 0);
        acc[nt] = __builtin_amdgcn_mfma_f32_16x16x32_bf16(a0, b2, acc[nt], 0, 0, 0);
        acc[nt] = __builtin_amdgcn_mfma_f32_16x16x32_bf16(a1, b1, acc[nt], 0, 0, 0);
        acc[nt] = __builtin_amdgcn_mfma_f32_16x16x32_bf16(a2, b0, acc[nt], 0, 0, 0);
      }
    }
    __syncthreads();
  }

  // C/D: row = q*4 + v (token), col = m (expert within n-tile)  [m89/m91]
  double* base = partial + (size_t)blockIdx.y * TOK * NE;
#pragma unroll
  for (int nt = 0; nt < 4; ++nt)
#pragma unroll
    for (int v = 0; v < 4; ++v)
      base[(size_t)(t0 + w * 16 + q * 4 + v) * NE + nt * 16 + m] =
          (double)acc[nt][v];
}

// ---------------- 3. softmax + top-8 per token (one wave64/token) ----------
__global__ __launch_bounds__(256) void topk_kernel(
    const double* __restrict__ partial, int nsplit,
    int* __restrict__ idx_kt, float* __restrict__ w_kt) {
  const int gid  = blockIdx.x * blockDim.x + threadIdx.x;
  const int t    = gid >> 6;
  const int lane = gid & 63;

  double v = 0.0;
  for (int p = 0; p < nsplit; ++p)
    v += partial[(size_t)p * TOK * NE + (size_t)t * NE + lane];

  double m = v;
#pragma unroll
  for (int off = 32; off; off >>= 1) {
    double o = __shfl_xor(m, off);
    m = o > m ? o : m;
  }
  double g = exp(v - m);
  double s = g;
#pragma unroll
  for (int off = 32; off; off >>= 1) s += __shfl_xor(s, off);
  double gate = g / s;

  float key = (float)gate;    // fp32-rounded key, tie -> lower index
  double ssel = 0.0;
  int my_k = -1;
#pragma unroll
  for (int k = 0; k < NK; ++k) {
    float bv = key;
    int   bi = lane;
#pragma unroll
    for (int off = 32; off; off >>= 1) {
      float ov = __shfl_xor(bv, off);
      int   oi = __shfl_xor(bi, off);
      if (ov > bv || (ov == bv && oi < bi)) { bv = ov; bi = oi; }
    }
    ssel += __shfl(gate, bi);
    if (lane == bi) { my_k = k; key = -1.0f; }
  }
  double gs = ssel;
  const double eps = (double)1.1920929e-07f;
  if (gs < eps) gs = eps;

  if (my_k >= 0) {
    idx_kt[my_k * TOK + t] = lane;
    w_kt [my_k * TOK + t] = (float)(gate / gs);
  }
}

// ---------------- 4. fused rank + scatter ------------------------------
__global__ __launch_bounds__(1024) void rank_scatter(
    const int* __restrict__ idx_kt, const float* __restrict__ w_kt,
    float* __restrict__ out, int C) {
  const int e    = blockIdx.x;
  const int tid  = threadIdx.x;
  const int lane = tid & 63;
  const int w    = tid >> 6;          // 0..15
  __shared__ int wt[16];
  int running = 0;
  const unsigned long long below = (1ull << lane) - 1ull;

  for (int i0 = 0; i0 < NK * TOK; i0 += 1024) {
    const int i = i0 + tid;
    const bool mhit = (idx_kt[i] == e);
    unsigned long long mask = __ballot(mhit);
    if (lane == 0) wt[w] = __popcll(mask);
    __syncthreads();
    int woff = 0, tot = 0;
#pragma unroll
    for (int j = 0; j < 16; ++j) {
      int c = wt[j];
      tot += c;
      if (j < w) woff += c;
    }
    if (mhit) {
      const int c = running + woff + __popcll(mask & below);
      if (c < C) {
        const int t = i & (TOK - 1);
        size_t off = ((size_t)t * NE + e) * (size_t)C + (size_t)c;
        out[off] = w_kt[i];                          // combine_weights
        out[(size_t)TOK * NE * C + off] = 1.0f;      // dispatch_mask
      }
    }
    running += tot;
    __syncthreads();
  }
}

extern "C" void kernel_launch(void* const* d_in, const int* in_sizes, int n_in,
                              void* d_out, int out_size, void* d_ws, size_t ws_size,
                              hipStream_t stream) {
  const float* x  = (const float*)d_in[0];   // [4096,4096]
  const float* wg = (const float*)d_in[1];   // [64,4096]
  float* out = (float*)d_out;

  const int C = out_size / (2 * TOK * NE);   // capacity from output size

  const size_t psz    = (size_t)NSPLIT * TOK * NE * sizeof(double);  // 16 MB
  const size_t tailsz = 2 * (size_t)NK * TOK * sizeof(int);          // 256 KB
  const size_t xsz    = (size_t)TOK * HID * sizeof(float);           // 64 MB

  char* ws = (char*)d_ws;
  double* partial = (double*)ws;
  int*    idx_kt  = (int*)  (ws + psz);
  float*  w_kt    = (float*)(ws + psz + (size_t)NK * TOK * sizeof(int));
  // xcopy goes after the tail buffers, 256B-aligned
  const size_t xoff = (psz + tailsz + 255) & ~(size_t)255;
  const bool   have_copy = (xoff + xsz) <= ws_size;
  float* xcopy = have_copy ? (float*)(ws + xoff) : nullptr;

  const int ncopy = have_copy ? 256 : 0;
  const int nfill = 2048;
  const int kchunk = HID / NSPLIT;   // 512
  const float* xsrc = have_copy ? xcopy : x;

  fill_copy   <<<ncopy + nfill, 256, 0, stream>>>(x, xcopy, ncopy, nfill,
                                                  out, out_size);
  dim3 bgrid(TOK / 64, NSPLIT);      // 64 x 8 = 512 blocks
  gemm_bf16x3 <<<bgrid, 256, 0, stream>>>(xsrc, wg, partial, kchunk);
  topk_kernel <<<TOK * 64 / 256, 256, 0, stream>>>(partial, NSPLIT, idx_kt, w_kt);
  rank_scatter<<<NE, 1024, 0, stream>>>(idx_kt, w_kt, out, C);
}

// Round 7
// 1267.647 us; speedup vs baseline: 1.0193x; 1.0193x over previous
//
#include <hip/hip_runtime.h>
#include <hip/hip_bf16.h>

// HunyuanTopKGate: x[4096,4096] fp32, wg[64,4096] fp32 ->
//   combine_weights [T,E,C] fp32 ++ dispatch_mask [T,E,C] (as fp32 0/1)
// C = 2268 -> 4.76 GB output zero-fill (~760us at 6.2 TB/s) is pole #1.
//
// Round 17: R16 killed the x-ingest theory. Hard-fact decomposition from
// R15 (3 dispatches, mega absent from top-5 cutoff 754.9): mega(fill+
// gemm) < 755  =>  topk + rank_scatter ~= 515us. The tail kernels are
// the only code unchanged all session -- that's why nothing ever moved.
// Suspects: rank_scatter's 32 serial iters x 2 block barriers with a
// global-latency load each (latency chain), and topk's 16 uncoalesced
// 4B store-lines per wave. Fix: (a) topk stores -> [t*8+k] layout (8
// winner lanes hit one 32B line; MATH UNTOUCHED -> absmax must stay
// 0.0004882812); (b) scatter2: one block/expert, one pass, one LDS scan
// (~10 barriers vs 64), then scatter. mega is R15-verbatim. 3 dispatches.
// Predict ~820-900 if the tail was the sink; if ~1270 persists the
// constant is harness-level -> roofline next round.
//
// ws: partial[8][4096][64] f64 (16MB) | idx8[4096*8] int | w8[4096*8] float

#define TOK 4096
#define HID 4096
#define NE  64
#define NK  8
#define NSPLIT 8

typedef __attribute__((ext_vector_type(8))) short short8;   // 8 bf16
typedef __attribute__((ext_vector_type(4))) float f32x4;

__device__ __forceinline__ short f2bf(float f) {
  __hip_bfloat16 h = __float2bfloat16(f);   // RNE
  return *reinterpret_cast<short*>(&h);
}
__device__ __forceinline__ float bf2f(short s) {
  unsigned u = ((unsigned)(unsigned short)s) << 16;
  return __uint_as_float(u);
}
__device__ __forceinline__ void cvt3(float f, short& s0, short& s1, short& s2) {
  s0 = f2bf(f);
  float r1 = f - bf2f(s0);
  s1 = f2bf(r1);
  float r2 = r1 - bf2f(s1);
  s2 = f2bf(r2);
}

// ---------------- 1. mega: R10 gemm blocks + plain-store fill blocks ------
// (R15 verbatim -- proven < 755us with fill+gemm fused)
__global__ __launch_bounds__(256) void mega(
    const float* __restrict__ x, const float* __restrict__ wg,
    double* __restrict__ partial, int kchunk, int ngemm, int nfill,
    float* __restrict__ out, int out_n) {
  const int bx  = blockIdx.x;
  const int tid = threadIdx.x;

  if (bx >= ngemm) {                    // ---- fill branch ----
    const int    fid    = bx - ngemm;
    const size_t n4     = ((size_t)(unsigned)out_n) >> 2;
    const size_t stride = (size_t)nfill * 256;
    f32x4* o4 = (f32x4*)out;
    const f32x4 z4 = (f32x4){0.f, 0.f, 0.f, 0.f};
    size_t i = (size_t)fid * 256 + tid;
    for (; i + 3 * stride < n4; i += 4 * stride) {
      o4[i]              = z4;
      o4[i + stride]     = z4;
      o4[i + 2 * stride] = z4;
      o4[i + 3 * stride] = z4;
    }
    for (; i < n4; i += stride) o4[i] = z4;
    if (fid == 0 && tid == 0)           // out_n % 4 == 0 -> empty, kept safe
      for (size_t i2 = n4 << 2; i2 < (size_t)(unsigned)out_n; ++i2) out[i2] = 0.f;
    return;
  }

  // ---- gemm branch (R10 verbatim) ----
  __shared__ __align__(16) short XA[3][64][72];   // 27.6 KB
  __shared__ __align__(16) short WB[3][64][72];   // 27.6 KB
  const int tileid = bx & 63;
  const int slab   = bx >> 6;
  const int t0   = tileid * 64;
  const int k0   = slab * kchunk;
  const int lane = tid & 63;
  const int w    = tid >> 6;
  const int m    = lane & 15;       // frag row/col within 16
  const int q    = lane >> 4;       // quad
  const int lrow = tid >> 2;        // staging: 4 threads per row
  const int lq   = tid & 3;         // 16 floats each

  f32x4 acc[4];
#pragma unroll
  for (int nt = 0; nt < 4; ++nt) acc[nt] = (f32x4){0.f, 0.f, 0.f, 0.f};

  for (int s = 0; s < kchunk; s += 64) {
    const int kk = k0 + s;
#pragma unroll
    for (int c = 0; c < 4; ++c) {
      const int col = lq * 16 + c * 4;
      float4 xv = *(const float4*)&x [(size_t)(t0 + lrow) * HID + kk + col];
      float4 wv = *(const float4*)&wg[(size_t)lrow * HID + kk + col];
      short4 p0, p1, p2;
      cvt3(xv.x, p0.x, p1.x, p2.x);  cvt3(xv.y, p0.y, p1.y, p2.y);
      cvt3(xv.z, p0.z, p1.z, p2.z);  cvt3(xv.w, p0.w, p1.w, p2.w);
      *(short4*)&XA[0][lrow][col] = p0;
      *(short4*)&XA[1][lrow][col] = p1;
      *(short4*)&XA[2][lrow][col] = p2;
      cvt3(wv.x, p0.x, p1.x, p2.x);  cvt3(wv.y, p0.y, p1.y, p2.y);
      cvt3(wv.z, p0.z, p1.z, p2.z);  cvt3(wv.w, p0.w, p1.w, p2.w);
      *(short4*)&WB[0][lrow][col] = p0;
      *(short4*)&WB[1][lrow][col] = p1;
      *(short4*)&WB[2][lrow][col] = p2;
    }
    __syncthreads();
#pragma unroll
    for (int kc = 0; kc < 64; kc += 32) {
      short8 a0 = *(const short8*)&XA[0][w * 16 + m][kc + q * 8];
      short8 a1 = *(const short8*)&XA[1][w * 16 + m][kc + q * 8];
      short8 a2 = *(const short8*)&XA[2][w * 16 + m][kc + q * 8];
#pragma unroll
      for (int nt = 0; nt < 4; ++nt) {
        short8 b0 = *(const short8*)&WB[0][nt * 16 + m][kc + q * 8];
        short8 b1 = *(const short8*)&WB[1][nt * 16 + m][kc + q * 8];
        short8 b2 = *(const short8*)&WB[2][nt * 16 + m][kc + q * 8];
        acc[nt] = __builtin_amdgcn_mfma_f32_16x16x32_bf16(a0, b0, acc[nt], 0, 0, 0);
        acc[nt] = __builtin_amdgcn_mfma_f32_16x16x32_bf16(a0, b1, acc[nt], 0, 0, 0);
        acc[nt] = __builtin_amdgcn_mfma_f32_16x16x32_bf16(a1, b0, acc[nt], 0, 0, 0);
        acc[nt] = __builtin_amdgcn_mfma_f32_16x16x32_bf16(a0, b2, acc[nt], 0, 0, 0);
        acc[nt] = __builtin_amdgcn_mfma_f32_16x16x32_bf16(a1, b1, acc[nt], 0, 0, 0);
        acc[nt] = __builtin_amdgcn_mfma_f32_16x16x32_bf16(a2, b0, acc[nt], 0, 0, 0);
      }
    }
    __syncthreads();
  }

  // C/D: row = q*4 + v (token), col = m (expert within n-tile)  [m89/m91]
  double* base = partial + (size_t)slab * TOK * NE;
#pragma unroll
  for (int nt = 0; nt < 4; ++nt)
#pragma unroll
    for (int v = 0; v < 4; ++v)
      base[(size_t)(t0 + w * 16 + q * 4 + v) * NE + nt * 16 + m] =
          (double)acc[nt][v];
}

// ---------------- 2. softmax + top-8 per token (one wave64/token) ----------
// Math IDENTICAL to the verified version; ONLY the two store lines
// changed to [t*8+k] layout (8 winner lanes -> one 32B line each buffer).
__global__ __launch_bounds__(256) void topk_kernel(
    const double* __restrict__ partial, int nsplit,
    int* __restrict__ idx8, float* __restrict__ w8) {
  const int gid  = blockIdx.x * blockDim.x + threadIdx.x;
  const int t    = gid >> 6;
  const int lane = gid & 63;

  double v = 0.0;
  for (int p = 0; p < nsplit; ++p)
    v += partial[(size_t)p * TOK * NE + (size_t)t * NE + lane];

  double m = v;
#pragma unroll
  for (int off = 32; off; off >>= 1) {
    double o = __shfl_xor(m, off);
    m = o > m ? o : m;
  }
  double g = exp(v - m);
  double s = g;
#pragma unroll
  for (int off = 32; off; off >>= 1) s += __shfl_xor(s, off);
  double gate = g / s;

  float key = (float)gate;    // fp32-rounded key, tie -> lower index
  double ssel = 0.0;
  int my_k = -1;
#pragma unroll
  for (int k = 0; k < NK; ++k) {
    float bv = key;
    int   bi = lane;
#pragma unroll
    for (int off = 32; off; off >>= 1) {
      float ov = __shfl_xor(bv, off);
      int   oi = __shfl_xor(bi, off);
      if (ov > bv || (ov == bv && oi < bi)) { bv = ov; bi = oi; }
    }
    ssel += __shfl(gate, bi);
    if (lane == bi) { my_k = k; key = -1.0f; }
  }
  double gs = ssel;
  const double eps = (double)1.1920929e-07f;
  if (gs < eps) gs = eps;

  if (my_k >= 0) {
    idx8[t * 8 + my_k] = lane;
    w8 [t * 8 + my_k] = (float)(gate / gs);
  }
}

// ---------------- 3. scatter2: one pass + one LDS scan ---------------------
// One block per expert e, 1024 threads. Flat order i = k*TOK + t (the
// reference's k-major cumsum order). Thread tid owns the contiguous
// 32-item segment [tid*32, tid*32+32) (k is constant in a segment).
// Phase A: count hits + bitmask. Hillis-Steele scan (10 steps) gives the
// exclusive prefix = capacity slot base. Phase B: scatter hits.
__global__ __launch_bounds__(1024) void scatter2(
    const int* __restrict__ idx8, const float* __restrict__ w8,
    float* __restrict__ out, int C) {
  const int e   = blockIdx.x;
  const int tid = threadIdx.x;
  __shared__ int sa[1024];
  __shared__ int sb[1024];

  const int base = tid * 32;           // item index base; k = base>>12 const
  const int k    = base >> 12;
  const int tbase = base & (TOK - 1);
  unsigned mask = 0u;
  int cnt = 0;
#pragma unroll 8
  for (int s = 0; s < 32; ++s) {
    if (idx8[(tbase + s) * 8 + k] == e) { mask |= (1u << s); ++cnt; }
  }

  sa[tid] = cnt;
  __syncthreads();
  int* src = sa; int* dst = sb;
  for (int off = 1; off < 1024; off <<= 1) {
    int v = src[tid];
    if (tid >= off) v += src[tid - off];
    dst[tid] = v;
    __syncthreads();
    int* tmp = src; src = dst; dst = tmp;
  }
  int c = src[tid] - cnt;              // exclusive prefix in flat order

  for (unsigned mm = mask; mm; mm &= (mm - 1)) {
    const int s = __builtin_ctz(mm);
    const int t = tbase + s;
    if (c < C) {
      const float wv = w8[t * 8 + k];
      const size_t off2 = ((size_t)t * NE + e) * (size_t)C + (size_t)c;
      out[off2] = wv;                          // combine_weights
      out[(size_t)TOK * NE * C + off2] = 1.0f; // dispatch_mask
    }
    ++c;
  }
}

extern "C" void kernel_launch(void* const* d_in, const int* in_sizes, int n_in,
                              void* d_out, int out_size, void* d_ws, size_t ws_size,
                              hipStream_t stream) {
  const float* x  = (const float*)d_in[0];   // [4096,4096]
  const float* wg = (const float*)d_in[1];   // [64,4096]
  float* out = (float*)d_out;

  const int C = out_size / (2 * TOK * NE);   // capacity from output size

  char* ws = (char*)d_ws;
  double* partial = (double*)ws;
  const size_t psz = (size_t)NSPLIT * TOK * NE * sizeof(double);   // 16 MB
  int*    idx8 = (int*)  (ws + psz);
  float*  w8   = (float*)(ws + psz + (size_t)NK * TOK * sizeof(int));

  const int kchunk = HID / NSPLIT;   // 512
  const int ngemm  = 64 * NSPLIT;    // 512 gemm blocks
  const int nfill  = 2048;           // plain-store fill blocks

  mega       <<<ngemm + nfill, 256, 0, stream>>>(x, wg, partial, kchunk,
                                                 ngemm, nfill, out, out_size);
  topk_kernel<<<TOK * 64 / 256, 256, 0, stream>>>(partial, NSPLIT, idx8, w8);
  scatter2   <<<NE, 1024, 0, stream>>>(idx8, w8, out, C);
}